// Round 7
// baseline (464.782 us; speedup 1.0000x reference)
//
#include <hip/hip_runtime.h>

#define TT  1024
#define DIN 8

// sigma(x) = 1 / (1 + exp2(-x*log2e))
__device__ __forceinline__ float fsig(float x) {
    float e = __builtin_amdgcn_exp2f(-1.4426950408889634f * x);
    return __builtin_amdgcn_rcpf(1.0f + e);
}
// tanh(x) = 2*sigma(2x) - 1
__device__ __forceinline__ float ftanh_(float x) {
    float e = __builtin_amdgcn_exp2f(-2.8853900817779268f * x);
    return 2.0f * __builtin_amdgcn_rcpf(1.0f + e) - 1.0f;
}
// DPP lane permute, compile-time ctrl. 0xB1 = quad_perm(1,0,3,2) (swap 2k<->2k+1)
// 0x114 = row_shr:4 (lane i <- i-4), 0x112 = row_shr:2, 0x102 = row_shl:2 (i <- i+2)
template<int CTRL>
__device__ __forceinline__ float dppf(float v) {
    return __uint_as_float((unsigned)__builtin_amdgcn_update_dpp(
        0, (int)__float_as_uint(v), CTRL, 0xF, 0xF, true));
}
// lgkm-only barrier. __syncthreads() drains vmcnt(0) too, which stalls every
// iteration on the global out-store ack + x prefetch. Correctness needs only:
//  (a) my ds_writes visible before I signal arrival  -> lgkmcnt(0)
//  (b) my ds_reads of the old parity slot complete before anyone overwrites it
//      next iteration                                -> lgkmcnt(0)
// Global stores are never read back; x-prefetch is same-wave consumed with
// compiler-tracked waits. Single asm block = no compiler-visible gap for
// ds ops to sink into (memory clobber fences the compiler both sides).
__device__ __forceinline__ void bar_lgkm() {
    asm volatile("s_waitcnt lgkmcnt(0)\n\ts_barrier" ::: "memory");
}

// 8 waves / batch element (block=512), layer-pipelined, 2 lanes per gate row.
// Lane l: ul=l>>3 (unit-local 0..7), g=(l>>1)&3 (i,f,g,o), part=l&1.
// Waves 0-3: layer 1 (16 h-wts + 4 x-wts per lane) + out-linear (16 wts,
//            col = wu*20 + l>>1, lanes<40), out runs 2 steps behind.
// Waves 4-7: layer 2 (32 wts: part0 = Whh2 row (h2 input), part1 = Wih2 (h1)).
// Half-sums combined via DPP quad_perm; cell update via DPP row_shr4/shr2/shl2
// onto the g-lanes (l&7 in {4,5}); lane l&7==4 publishes h to LDS.
// Pipeline at iter t: L1 -> h1(t); L2 -> h2(t-1); out(t-2). One barrier/iter.
__global__ void __launch_bounds__(512, 2)
lstm_pipe8(const float* __restrict__ x,
           const float* __restrict__ Wih1, const float* __restrict__ Whh1,
           const float* __restrict__ bih1, const float* __restrict__ bhh1,
           const float* __restrict__ Wih2, const float* __restrict__ Whh2,
           const float* __restrict__ bih2, const float* __restrict__ bhh2,
           const float* __restrict__ Wlin, const float* __restrict__ blin,
           float* __restrict__ out)
{
    const int tid  = threadIdx.x;
    const int wv   = tid >> 6;         // wave 0..7
    const int l    = tid & 63;
    const int part = l & 1;
    const int g    = (l >> 1) & 3;     // 0=i 1=f 2=g 3=o
    const int ul   = l >> 3;           // unit-local 0..7
    const int b    = blockIdx.x;
    const bool isL1 = (wv < 4);
    const int  wu   = isL1 ? wv : (wv - 4);
    const int  unit = wu*8 + ul;       // hidden unit 0..31
    const int  R    = g*32 + unit;     // gate row 0..127
    const bool isg  = (g == 2);

    __shared__ float hb1[2][32];       // h1 by parity
    __shared__ float hb2[2][32];       // h2 by parity
    if (tid < 64)       ((float*)hb1)[tid]      = 0.f;
    else if (tid < 128) ((float*)hb2)[tid - 64] = 0.f;

    // ---- per-lane weights ----
    float wg[20];          // L1: [0:16]=Whh1 half, [16:20]=Wih1 quarter
    float wg2[32];         // L2: full 32 input wts
    float wl[16];          // L1: out-linear half column
    float bias = 0.f, obias = 0.f;
    int ocol = 0;

    if (isL1) {
        const float* wsrc = Whh1 + R*32 + part*16;
#pragma unroll
        for (int qq = 0; qq < 4; ++qq) {
            float4 v = reinterpret_cast<const float4*>(wsrc)[qq];
            wg[4*qq]=v.x; wg[4*qq+1]=v.y; wg[4*qq+2]=v.z; wg[4*qq+3]=v.w;
        }
        float4 xv = *reinterpret_cast<const float4*>(Wih1 + R*DIN + part*4);
        wg[16]=xv.x; wg[17]=xv.y; wg[18]=xv.z; wg[19]=xv.w;
        if (!part) bias = bih1[R] + bhh1[R];
        ocol = wu*20 + (l >> 1);
        const int oc = (l < 40) ? ocol : 79;       // clamp: loads valid, unused
        const float* osrc = Wlin + oc*32 + part*16;
#pragma unroll
        for (int qq = 0; qq < 4; ++qq) {
            float4 v = reinterpret_cast<const float4*>(osrc)[qq];
            wl[4*qq]=v.x; wl[4*qq+1]=v.y; wl[4*qq+2]=v.z; wl[4*qq+3]=v.w;
        }
        if (!part) obias = blin[oc];
    } else {
        const float* wsrc = part ? (Wih2 + R*32) : (Whh2 + R*32);
#pragma unroll
        for (int qq = 0; qq < 8; ++qq) {
            float4 v = reinterpret_cast<const float4*>(wsrc)[qq];
            wg2[4*qq]=v.x; wg2[4*qq+1]=v.y; wg2[4*qq+2]=v.z; wg2[4*qq+3]=v.w;
        }
        if (!part) bias = bih2[R] + bhh2[R];
    }

    float c = 0.f;   // valid on lanes l&7 in {4,5}; bounded garbage elsewhere

    const float* __restrict__ xb = x   + (size_t)b * (TT*DIN);
    float* __restrict__ outb     = out + (size_t)b * (TT*80);

    float4 xcur;
    if (isL1) xcur = *reinterpret_cast<const float4*>(xb + part*4);  // x(0) half

    bar_lgkm();   // zero-init visible

#pragma unroll 1
    for (int t = 0; t <= TT + 1; ++t) {
        const int pm1 = (t - 1) & 1;
        const int p0  = t & 1;

        if (isL1) {
            // ---- issue ALL LDS reads up front: gate h1(t-1) + out h2(t-2) ----
            // (hb2 slots are zero-filled pre-loop, so unconditional reads are
            //  safe at t<2; the out value is just not stored then.)
            const float* hin = &hb1[pm1][part << 4];
            const float* hob = &hb2[p0][part << 4];
            float4 hg[4], ho[4];
#pragma unroll
            for (int qq = 0; qq < 4; ++qq) hg[qq] = reinterpret_cast<const float4*>(hin)[qq];
#pragma unroll
            for (int qq = 0; qq < 4; ++qq) ho[qq] = reinterpret_cast<const float4*>(hob)[qq];

            if (t < TT) {
                // L1 gate half-row: 16 h-FMA + 4 x-FMA
                float a0 = bias, a1 = 0.f, a2 = 0.f, a3 = 0.f;
#pragma unroll
                for (int qq = 0; qq < 4; ++qq) {
                    a0 += wg[4*qq]  *hg[qq].x; a1 += wg[4*qq+1]*hg[qq].y;
                    a2 += wg[4*qq+2]*hg[qq].z; a3 += wg[4*qq+3]*hg[qq].w;
                }
                a0 += wg[16]*xcur.x; a1 += wg[17]*xcur.y;
                a2 += wg[18]*xcur.z; a3 += wg[19]*xcur.w;
                // prefetch next x half (stays in flight across the barrier now)
                const int tn = (t + 1 < TT) ? (t + 1) : (TT - 1);
                xcur = *reinterpret_cast<const float4*>(xb + tn*DIN + part*4);

                float sum  = (a0 + a1) + (a2 + a3);
                float full = sum + dppf<0xB1>(sum);      // combine half-dots
                float u  = isg ? (full + full) : full;
                float S  = fsig(u);
                float av = isg ? (S + S - 1.0f) : S;     // tanh(g) | sigmoid
                // cell update on g-lanes (l&7 in {4,5}) via DPP
                float itg = dppf<0x114>(av) * av;        // sig(i)*tanh(g)
                float fv  = dppf<0x112>(av);             // sig(f)
                c = fv * c + itg;
                float so  = dppf<0x102>(av);             // sig(o)
                float hv  = so * ftanh_(c);
                if ((l & 7) == 4) hb1[p0][unit] = hv;    // publish h1(t)
            }
            if (t >= 2) {
                // out(t-2) half-column: 16 FMA (h2 already in registers)
                float o0 = obias, o1 = 0.f, o2 = 0.f, o3 = 0.f;
#pragma unroll
                for (int qq = 0; qq < 4; ++qq) {
                    o0 += wl[4*qq]  *ho[qq].x; o1 += wl[4*qq+1]*ho[qq].y;
                    o2 += wl[4*qq+2]*ho[qq].z; o3 += wl[4*qq+3]*ho[qq].w;
                }
                float osum  = (o0 + o1) + (o2 + o3);
                float ofull = osum + dppf<0xB1>(osum);
                if (!part && l < 40)
                    outb[(size_t)(t - 2)*80 + ocol] = ofull;   // fire-and-forget
            }
        } else {
            if (t >= 1 && t <= TT) {
                // L2 gate half-row: 32 FMA (part0: h2(t-2) wts, part1: h1(t-1))
                const float* hin = part ? &hb1[pm1][0] : &hb2[p0][0];
                float a0 = bias, a1 = 0.f, a2 = 0.f, a3 = 0.f;
#pragma unroll
                for (int qq = 0; qq < 8; ++qq) {
                    float4 v = reinterpret_cast<const float4*>(hin)[qq];
                    a0 += wg2[4*qq]  *v.x; a1 += wg2[4*qq+1]*v.y;
                    a2 += wg2[4*qq+2]*v.z; a3 += wg2[4*qq+3]*v.w;
                }
                float sum  = (a0 + a1) + (a2 + a3);
                float full = sum + dppf<0xB1>(sum);
                float u  = isg ? (full + full) : full;
                float S  = fsig(u);
                float av = isg ? (S + S - 1.0f) : S;
                float itg = dppf<0x114>(av) * av;
                float fv  = dppf<0x112>(av);
                c = fv * c + itg;
                float so  = dppf<0x102>(av);
                float hv  = so * ftanh_(c);
                if ((l & 7) == 4) hb2[pm1][unit] = hv;   // publish h2(t-1)
            }
        }

        bar_lgkm();
    }
}

extern "C" void kernel_launch(void* const* d_in, const int* in_sizes, int n_in,
                              void* d_out, int out_size, void* d_ws, size_t ws_size,
                              hipStream_t stream) {
    const float* x    = (const float*)d_in[0];
    const float* Wih1 = (const float*)d_in[1];
    const float* Whh1 = (const float*)d_in[2];
    const float* bih1 = (const float*)d_in[3];
    const float* bhh1 = (const float*)d_in[4];
    const float* Wih2 = (const float*)d_in[5];
    const float* Whh2 = (const float*)d_in[6];
    const float* bih2 = (const float*)d_in[7];
    const float* bhh2 = (const float*)d_in[8];
    const float* Wlin = (const float*)d_in[9];
    const float* blin = (const float*)d_in[10];

    const int B = in_sizes[0] / (TT * DIN);   // 256

    hipLaunchKernelGGL(lstm_pipe8, dim3(B), dim3(512), 0, stream,
                       x, Wih1, Whh1, bih1, bhh1,
                       Wih2, Whh2, bih2, bhh2, Wlin, blin,
                       (float*)d_out);
}